// Round 7
// baseline (287.985 us; speedup 1.0000x reference)
//
#include <hip/hip_runtime.h>

#define S 132                 // padded LDS row stride (floats) for gemm tiles
#define SCALE 10.0f           // 1 / TEMPERATURE
#define EPS_MARGIN 0.008f     // 2 * (bf16 unit-dot hard error bound)
#define SROWS_CAP 480         // per-strip flagged-row cap (expect ~170 @ 32 strips)
#define ROWCHUNK 48           // rows per rescreen chunk (3 x 16-row MFMA tiles)

typedef __attribute__((ext_vector_type(8))) short short8;
typedef __attribute__((ext_vector_type(4))) float floatx4;

#define MFMA16(a, b, c) __builtin_amdgcn_mfma_f32_16x16x32_bf16((a), (b), (c), 0, 0, 0)

// ---------- helpers ----------
__device__ __forceinline__ unsigned int ordered_bits(float f) {
    unsigned int b = __float_as_uint(f);
    return (b & 0x80000000u) ? ~b : (b | 0x80000000u);
}
__device__ __forceinline__ float from_ordered(unsigned int u) {
    return __uint_as_float((u & 0x80000000u) ? (u ^ 0x80000000u) : ~u);
}
__device__ __forceinline__ short bf_rne(float x) {   // fp32 -> bf16 bits, RNE
    unsigned int u = __float_as_uint(x);
    return (short)((u + 0x7FFFu + ((u >> 16) & 1u)) >> 16);
}
__device__ __forceinline__ float bf2f(short s) {
    return __uint_as_float(((unsigned int)(unsigned short)s) << 16);
}

// ---------- K1: fused prep (l2-norm + init) and queue bf16 convert ----------
__global__ __launch_bounds__(256) void k_prep_qcvt(const float* __restrict__ p1,
                                                   const float* __restrict__ p2,
                                                   const float* __restrict__ queue,
                                                   float* __restrict__ pn,
                                                   short* __restrict__ pnb,
                                                   short* __restrict__ qb,
                                                   unsigned int* __restrict__ mbest,
                                                   unsigned long long* __restrict__ best,
                                                   float* __restrict__ sums) {
    int b = blockIdx.x;
    if (b < 1024) {
        int sub = threadIdx.x >> 6;     // wave 0..3 -> one row each
        int t = threadIdx.x & 63;
        int row = b * 4 + sub;          // 0..4095
        const float* src = (row < 2048) ? (p1 + (size_t)row * 128)
                                        : (p2 + (size_t)(row - 2048) * 128);
        float2 v = ((const float2*)src)[t];
        float ss = v.x * v.x + v.y * v.y;
        #pragma unroll
        for (int o = 32; o; o >>= 1) ss += __shfl_xor(ss, o);
        float inv = 1.0f / sqrtf(ss);
        float2 o2; o2.x = v.x * inv; o2.y = v.y * inv;
        ((float2*)(pn + (size_t)row * 128))[t] = o2;
        unsigned int pk = (unsigned int)(unsigned short)bf_rne(o2.x)
                        | ((unsigned int)(unsigned short)bf_rne(o2.y) << 16);
        ((unsigned int*)(pnb + (size_t)row * 128))[t] = pk;
        if (t == 0) { mbest[row] = 0u; best[row] = 0ULL; }
        if (row < 128) sums[row * 64 + t] = 0.0f;
    } else {
        size_t i = ((size_t)(b - 1024) * 256 + threadIdx.x) * 8;
        float4 f0 = *(const float4*)(queue + i);
        float4 f1 = *(const float4*)(queue + i + 4);
        short8 o;
        o[0] = bf_rne(f0.x); o[1] = bf_rne(f0.y); o[2] = bf_rne(f0.z); o[3] = bf_rne(f0.w);
        o[4] = bf_rne(f1.x); o[5] = bf_rne(f1.y); o[6] = bf_rne(f1.z); o[7] = bf_rne(f1.w);
        *(short8*)(qb + i) = o;
    }
}

// ---------- screen primitives (rf = 4) ----------
__device__ __forceinline__ void loadB4(short8 B[4], const short* p) {
    #pragma unroll
    for (int kk = 0; kk < 4; ++kk) B[kk] = *(const short8*)(p + kk * 32);
}
__device__ __forceinline__ void chain4(const short8 A[4][4], const short8 B[4],
                                       floatx4 acc[4]) {
    floatx4 zero = {0.0f, 0.0f, 0.0f, 0.0f};
    #pragma unroll
    for (int rf = 0; rf < 4; ++rf) acc[rf] = MFMA16(A[rf][0], B[0], zero);
    #pragma unroll
    for (int rf = 0; rf < 4; ++rf) acc[rf] = MFMA16(A[rf][1], B[1], acc[rf]);
    #pragma unroll
    for (int rf = 0; rf < 4; ++rf) acc[rf] = MFMA16(A[rf][2], B[2], acc[rf]);
    #pragma unroll
    for (int rf = 0; rf < 4; ++rf) acc[rf] = MFMA16(A[rf][3], B[3], acc[rf]);
}
__device__ __forceinline__ void fmax4(float rmax[4][4], const floatx4 acc[4]) {
    #pragma unroll
    for (int rf = 0; rf < 4; ++rf)
        #pragma unroll
        for (int r = 0; r < 4; ++r) rmax[rf][r] = fmaxf(rmax[rf][r], acc[rf][r]);
}

// ---------- K2: single bf16 MFMA screen pass (deferred-fmax dual-acc) --------
// Grid 256 = 8 rowblocks x 32 qsplits (2048 q), block = 8 waves (512 thr) all
// on the SAME strip (L1 B-sharing), 1 block/CU, 2 waves/SIMD. Wave owns 64
// rows (A[4][4] = 64 VGPR). KEY CHANGE vs rounds 2-6: two named acc sets with
// the fmax consuming the PREVIOUS tile's accumulators -- the old same-tile
// MFMA->fmax dependency stalled the wave ~600+ cyc/tile waiting for chained
// MFMA results (the unexplained 48% idle; MfmaUtil 31%). Distance-1 producer
// means fmax never waits; MFMA issue is throttled only by pipe backpressure.
// Per-(row,q) accumulation order (kk 0..3 chained from zero) is IDENTICAL to
// k_rescreen -> bit-exact scores -> certificate semantics unchanged.
__global__ __launch_bounds__(512, 2) void k_screen(const short* __restrict__ pnb,
                                                   const short* __restrict__ qb,
                                                   unsigned int* __restrict__ mbest,
                                                   float* __restrict__ smax) {
    int tid = threadIdx.x;
    int lane = tid & 63, wv = tid >> 6;        // 8 waves
    int n16 = lane & 15, quad = lane >> 4;

    int id = blockIdx.x;                // 0..255
    int xcd = id & 7;
    int g = id >> 3;                    // 0..31
    int rowblk = g & 7;                 // 8 rowblocks of 512 rows
    int qsub = g >> 3;                  // 0..3
    int qsplit = xcd * 4 + qsub;        // 32 strips of 2048 q, XCD-local (512 KB)
    int rowbase = rowblk * 512 + wv * 64;
    int qstart = qsplit * 2048;

    // A fragments: 4 row-groups x 4 k-groups.
    short8 A[4][4];
    #pragma unroll
    for (int rf = 0; rf < 4; ++rf) {
        const short* ap = pnb + (size_t)(rowbase + rf * 16 + n16) * 128 + quad * 8;
        #pragma unroll
        for (int kk = 0; kk < 4; ++kk)
            A[rf][kk] = *(const short8*)(ap + kk * 32);
    }

    float rmax[4][4];
    #pragma unroll
    for (int rf = 0; rf < 4; ++rf)
        #pragma unroll
        for (int r = 0; r < 4; ++r) rmax[rf][r] = -1e30f;

    const short* lp = qb + (size_t)(qstart + n16) * 128 + quad * 8;
    short8 Ba[4], Bb[4];
    floatx4 accA[4], accB[4];

    // prologue: tile 0 -> accB; tile 1 loaded into Bb
    loadB4(Ba, lp);
    chain4(A, Ba, accB);
    loadB4(Bb, lp + 2048);

    // 128 tiles of 16 q; loop covers tiles 1..126, epilogue tile 127.
    for (int t = 1; t < 127; t += 2) {
        if (((t - 1) & 15) == 0) __syncthreads();   // keep 8 waves converged
        loadB4(Ba, lp + (size_t)(t + 1) * 2048);    // tile t+1
        chain4(A, Bb, accA);                        // tile t
        fmax4(rmax, accB);                          // tile t-1 (long ready)
        loadB4(Bb, lp + (size_t)(t + 2) * 2048);    // tile t+2 (max 127)
        chain4(A, Ba, accB);                        // tile t+1
        fmax4(rmax, accA);                          // tile t
    }
    chain4(A, Bb, accA);                            // tile 127
    fmax4(rmax, accB);                              // tile 126
    fmax4(rmax, accA);                              // tile 127

    #pragma unroll
    for (int rf = 0; rf < 4; ++rf)
        #pragma unroll
        for (int r = 0; r < 4; ++r) {
            float v = rmax[rf][r];
            v = fmaxf(v, __shfl_xor(v, 1));
            v = fmaxf(v, __shfl_xor(v, 2));
            v = fmaxf(v, __shfl_xor(v, 4));
            v = fmaxf(v, __shfl_xor(v, 8));
            if (n16 == 0) {
                int row = rowbase + rf * 16 + quad * 4 + r;
                atomicMax(&mbest[row], ordered_bits(v));
                smax[(size_t)qsplit * 4096 + row] = v;   // exact fp32 strip max
            }
        }
}

// ---------- K3: fused rescreen (row-scan + bf16 re-score + exact rerank) -----
// Grid 1024 = 32 strips x 32 qparts. Each block rebuilds its strip's flagged-
// row list (smax + mbest scan, L2-resident), then re-runs the IDENTICAL MFMA
// chain for flagged rows x its 4 q-tiles. On a threshold hit the wave computes
// the exact fp32 dot inline (bit-identical to the old k_rerank reduction) and
// atomicMax's best[].
__global__ __launch_bounds__(256, 4) void k_rescreen(const short* __restrict__ pnb,
                                                     const short* __restrict__ qb,
                                                     const unsigned int* __restrict__ mbest,
                                                     const float* __restrict__ smax,
                                                     const float* __restrict__ pn,
                                                     const float* __restrict__ queue,
                                                     unsigned long long* __restrict__ best) {
    __shared__ unsigned short rows[SROWS_CAP];
    __shared__ int nsh;
    int b = blockIdx.x;
    int s = b & 31;                     // strip 0..31 (2048 q)
    int qp = b >> 5;                    // 0..31
    int tid = threadIdx.x;
    if (tid == 0) nsh = 0;
    __syncthreads();
    const float* sm = smax + (size_t)s * 4096;
    #pragma unroll
    for (int j = 0; j < 16; ++j) {
        int row = tid + 256 * j;
        float thr = from_ordered(mbest[row]) - EPS_MARGIN;
        if (sm[row] > thr) {
            int pos = atomicAdd(&nsh, 1);
            if (pos < SROWS_CAP) rows[pos] = (unsigned short)row;
        }
    }
    __syncthreads();
    int n = nsh; if (n > SROWS_CAP) n = SROWS_CAP;
    if (n == 0) return;

    int lane = tid & 63, wv = tid >> 6;
    int n16 = lane & 15, quad = lane >> 4;
    int qt = qp * 4 + wv;               // q-tile 0..127 within strip
    int qrow = s * 2048 + qt * 16 + n16;    // this lane's q column index

    // B fragment (identical mapping to k_screen)
    const short* bp = qb + (size_t)qrow * 128 + quad * 8;
    short8 b0 = *(const short8*)(bp);
    short8 b1 = *(const short8*)(bp + 32);
    short8 b2 = *(const short8*)(bp + 64);
    short8 b3 = *(const short8*)(bp + 96);

    for (int base = 0; base < n; base += ROWCHUNK) {
        // Fixed 3 row-tiles (static indexing -> registers); invalid lanes get
        // a clamped A row and thr=+inf so they never hit.
        short8 Af[3][4]; float th[3][4]; int rowC[3][4];
        #pragma unroll
        for (int rt = 0; rt < 3; ++rt) {
            int ia = base + rt * 16 + n16;
            int rA = rows[ia < n ? ia : base];
            const short* ap = pnb + (size_t)rA * 128 + quad * 8;
            #pragma unroll
            for (int kk = 0; kk < 4; ++kk) Af[rt][kk] = *(const short8*)(ap + kk * 32);
            #pragma unroll
            for (int r = 0; r < 4; ++r) {
                int ic = base + rt * 16 + quad * 4 + r;
                if (ic < n) {
                    int rr = rows[ic];
                    rowC[rt][r] = rr;
                    th[rt][r] = from_ordered(mbest[rr]) - EPS_MARGIN;
                } else { rowC[rt][r] = 0; th[rt][r] = 3.0e38f; }
            }
        }
        #pragma unroll
        for (int rt = 0; rt < 3; ++rt) {
            floatx4 zero = {0.0f, 0.0f, 0.0f, 0.0f};
            floatx4 acc = MFMA16(Af[rt][0], b0, zero);
            acc = MFMA16(Af[rt][1], b1, acc);
            acc = MFMA16(Af[rt][2], b2, acc);
            acc = MFMA16(Af[rt][3], b3, acc);
            #pragma unroll
            for (int r = 0; r < 4; ++r) {
                unsigned long long mb = __ballot(acc[r] > th[rt][r]);
                while (mb) {            // rare path: exact fp32 rerank, whole wave
                    int L = __builtin_ctzll(mb);
                    mb &= mb - 1;
                    int row = __shfl(rowC[rt][r], L);
                    int q   = __shfl(qrow, L);
                    float2 a  = ((const float2*)(pn + (size_t)row * 128))[lane];
                    float2 bq = ((const float2*)(queue + (size_t)q * 128))[lane];
                    float d = a.x * bq.x + a.y * bq.y;
                    #pragma unroll
                    for (int o = 32; o; o >>= 1) d += __shfl_xor(d, o);
                    if (lane == 0) {
                        unsigned long long pk = ((unsigned long long)ordered_bits(d) << 32)
                                              | (unsigned long long)(unsigned int)(~q);
                        atomicMax(&best[row], pk);
                    }
                }
            }
        }
    }
}

// ---------- K4: fused gather + A(bf16) @ B(fp32)^T -> exp-partial sums -------
__global__ __launch_bounds__(256) void k_gemm_lse(const unsigned long long* __restrict__ best,
                                                  const float* __restrict__ queue,
                                                  const float* __restrict__ pn,
                                                  float* __restrict__ sums,
                                                  float* __restrict__ dg) {
    __shared__ __align__(16) float al[64 * S];
    __shared__ __align__(16) float bl[64 * S];
    __shared__ float red[64][17];
    int tid = threadIdx.x;
    int z = blockIdx.z;
    const float* B = pn + (z ? 0 : 2048 * 128);
    float* rowsum = sums + z * 4096;
    float* colsum = sums + z * 4096 + 2048;
    float* diag = dg + z * 2048;
    int arow0 = z * 2048 + blockIdx.x * 64;

    #pragma unroll
    for (int i = tid; i < 1024; i += 256) {
        int r = i >> 4, c = (i & 15) * 8;
        unsigned int idx = (~(unsigned int)(best[arow0 + r] & 0xFFFFFFFFull)) & 0xFFFFu;
        const float* qr = queue + (size_t)idx * 128 + c;
        float4 f0 = *(const float4*)(qr);
        float4 f1 = *(const float4*)(qr + 4);
        float* dst = &al[r * S + c];
        dst[0] = bf2f(bf_rne(f0.x)); dst[1] = bf2f(bf_rne(f0.y));
        dst[2] = bf2f(bf_rne(f0.z)); dst[3] = bf2f(bf_rne(f0.w));
        dst[4] = bf2f(bf_rne(f1.x)); dst[5] = bf2f(bf_rne(f1.y));
        dst[6] = bf2f(bf_rne(f1.z)); dst[7] = bf2f(bf_rne(f1.w));
    }
    const float4* bsrc = (const float4*)(B + (size_t)blockIdx.y * 64 * 128);
    #pragma unroll
    for (int i = tid; i < 2048; i += 256) {
        int r = i >> 5, c = i & 31;
        *(float4*)&bl[r * S + c * 4] = bsrc[i];
    }
    __syncthreads();
    int ty = tid >> 4, tx = tid & 15;
    float acc[4][4] = {};
    #pragma unroll 2
    for (int k = 0; k < 128; k += 4) {
        float4 a[4], b[4];
        #pragma unroll
        for (int i = 0; i < 4; ++i) a[i] = *(const float4*)&al[(ty + 16 * i) * S + k];
        #pragma unroll
        for (int j = 0; j < 4; ++j) b[j] = *(const float4*)&bl[(tx + 16 * j) * S + k];
        #pragma unroll
        for (int i = 0; i < 4; ++i)
            #pragma unroll
            for (int j = 0; j < 4; ++j)
                acc[i][j] += a[i].x * b[j].x + a[i].y * b[j].y +
                             a[i].z * b[j].z + a[i].w * b[j].w;
    }
    int rowbase = blockIdx.x * 64, colbase = blockIdx.y * 64;

    float e[4][4], rs[4], cs[4];
    #pragma unroll
    for (int i = 0; i < 4; ++i) { rs[i] = 0.0f; cs[i] = 0.0f; }
    #pragma unroll
    for (int i = 0; i < 4; ++i)
        #pragma unroll
        for (int j = 0; j < 4; ++j) {
            e[i][j] = __expf(acc[i][j] * SCALE - 10.0f);
            rs[i] += e[i][j];
        }
    #pragma unroll
    for (int j = 0; j < 4; ++j)
        #pragma unroll
        for (int i = 0; i < 4; ++i) cs[j] += e[i][j];

    if (rowbase == colbase && ty == tx) {
        #pragma unroll
        for (int i = 0; i < 4; ++i) diag[rowbase + ty + 16 * i] = acc[i][i];
    }

    #pragma unroll
    for (int i = 0; i < 4; ++i) red[ty + 16 * i][tx] = rs[i];
    __syncthreads();
    if (tid < 64) {
        float s = 0.0f;
        #pragma unroll
        for (int x = 0; x < 16; ++x) s += red[tid][x];
        atomicAdd(&rowsum[rowbase + tid], s);
    }
    __syncthreads();
    #pragma unroll
    for (int j = 0; j < 4; ++j) red[tx + 16 * j][ty] = cs[j];
    __syncthreads();
    if (tid < 64) {
        float s = 0.0f;
        #pragma unroll
        for (int x = 0; x < 16; ++x) s += red[tid][x];
        atomicAdd(&colsum[colbase + tid], s);
    }
}

// ---------- K5: final loss ----------
__global__ void k_final(const float* __restrict__ sums,
                        const float* __restrict__ dg1, const float* __restrict__ dg2,
                        float* __restrict__ out) {
    int idx = blockIdx.x * 256 + threadIdx.x;    // 0..8191
    int seg = idx >> 11, r = idx & 2047;
    float s = sums[seg * 2048 + r];
    float d = (seg < 2) ? dg1[r] : dg2[r];
    out[idx] = 10.0f + logf(s) - d * SCALE;
}

extern "C" void kernel_launch(void* const* d_in, const int* in_sizes, int n_in,
                              void* d_out, int out_size, void* d_ws, size_t ws_size,
                              hipStream_t stream) {
    const float* p1    = (const float*)d_in[0];   // [2048,128]
    const float* p2    = (const float*)d_in[1];   // [2048,128]
    const float* queue = (const float*)d_in[2];   // [65536,128]
    float* out = (float*)d_out;                   // [8192]

    char* w = (char*)d_ws;                        // footprint ~20.1 MiB
    float* pn   = (float*)w;                              // 2 MB fp32 [4096,128]
    float* smax = (float*)(w + (2u << 20));               // 512 KB fp32 [32,4096]
    short* qb   = (short*)(w + (3u << 20));               // 16 MB bf16 [65536,128]
    short* pnb  = (short*)(w + (19u << 20));              // 1 MB bf16 [4096,128]
    char* b2 = w + (20u << 20);
    unsigned int* mbest = (unsigned int*)b2;                        // 16 KB
    unsigned long long* best = (unsigned long long*)(b2 + (16u << 10)); // 32 KB
    float* sums = (float*)(b2 + (48u << 10));                       // 32 KB
    float* dg1  = sums + 8192;                                      // 8 KB
    float* dg2  = dg1 + 2048;                                       // 8 KB

    k_prep_qcvt<<<5120, 256, 0, stream>>>(p1, p2, queue, pn, pnb, qb, mbest, best, sums);
    k_screen<<<256, 512, 0, stream>>>(pnb, qb, mbest, smax);
    k_rescreen<<<32 * 32, 256, 0, stream>>>(pnb, qb, mbest, smax, pn, queue, best);
    k_gemm_lse<<<dim3(32, 32, 2), 256, 0, stream>>>(best, queue, pn, sums, dg1);
    k_final<<<32, 256, 0, stream>>>(sums, dg1, dg2, out);
}

// Round 8
// 215.467 us; speedup vs baseline: 1.3366x; 1.3366x over previous
//
#include <hip/hip_runtime.h>

#define SCALE 10.0f           // 1 / TEMPERATURE
#define EPS_MARGIN 0.008f     // 2 * (bf16 unit-dot hard error bound)
#define SROWS_CAP 480         // per-strip flagged-row cap (expect ~85, sd ~9)
#define ROWCHUNK 48           // rows per rescreen chunk (3 x 16-row MFMA tiles)

typedef __attribute__((ext_vector_type(8))) short short8;
typedef __attribute__((ext_vector_type(4))) float floatx4;

#define MFMA16(a, b, c) __builtin_amdgcn_mfma_f32_16x16x32_bf16((a), (b), (c), 0, 0, 0)

// ---------- helpers ----------
__device__ __forceinline__ unsigned int ordered_bits(float f) {
    unsigned int b = __float_as_uint(f);
    return (b & 0x80000000u) ? ~b : (b | 0x80000000u);
}
__device__ __forceinline__ float from_ordered(unsigned int u) {
    return __uint_as_float((u & 0x80000000u) ? (u ^ 0x80000000u) : ~u);
}
__device__ __forceinline__ short bf_rne(float x) {   // fp32 -> bf16 bits, RNE
    unsigned int u = __float_as_uint(x);
    return (short)((u + 0x7FFFu + ((u >> 16) & 1u)) >> 16);
}
__device__ __forceinline__ float bf2f(short s) {
    return __uint_as_float(((unsigned int)(unsigned short)s) << 16);
}

// ---------- K1: fused prep (l2-norm + hi/lo bf16 + init) and queue convert ---
// Blocks 0..1023: 4 rows each -> pn fp32, pnb bf16 (hi), pnl bf16 (residual
// lo: pn - bf2f(pnb), for the gemm's B hi/lo split), init mbest/best, zero
// sums. Blocks 1024..5119: queue fp32 -> qb bf16.
__global__ __launch_bounds__(256) void k_prep_qcvt(const float* __restrict__ p1,
                                                   const float* __restrict__ p2,
                                                   const float* __restrict__ queue,
                                                   float* __restrict__ pn,
                                                   short* __restrict__ pnb,
                                                   short* __restrict__ pnl,
                                                   short* __restrict__ qb,
                                                   unsigned int* __restrict__ mbest,
                                                   unsigned long long* __restrict__ best,
                                                   float* __restrict__ sums) {
    int b = blockIdx.x;
    if (b < 1024) {
        int sub = threadIdx.x >> 6;     // wave 0..3 -> one row each
        int t = threadIdx.x & 63;
        int row = b * 4 + sub;          // 0..4095
        const float* src = (row < 2048) ? (p1 + (size_t)row * 128)
                                        : (p2 + (size_t)(row - 2048) * 128);
        float2 v = ((const float2*)src)[t];
        float ss = v.x * v.x + v.y * v.y;
        #pragma unroll
        for (int o = 32; o; o >>= 1) ss += __shfl_xor(ss, o);
        float inv = 1.0f / sqrtf(ss);
        float2 o2; o2.x = v.x * inv; o2.y = v.y * inv;
        ((float2*)(pn + (size_t)row * 128))[t] = o2;
        short hx = bf_rne(o2.x), hy = bf_rne(o2.y);
        unsigned int pk = (unsigned int)(unsigned short)hx
                        | ((unsigned int)(unsigned short)hy << 16);
        ((unsigned int*)(pnb + (size_t)row * 128))[t] = pk;
        short lx = bf_rne(o2.x - bf2f(hx)), ly = bf_rne(o2.y - bf2f(hy));
        unsigned int pl = (unsigned int)(unsigned short)lx
                        | ((unsigned int)(unsigned short)ly << 16);
        ((unsigned int*)(pnl + (size_t)row * 128))[t] = pl;
        if (t == 0) { mbest[row] = 0u; best[row] = 0ULL; }
        if (row < 128) sums[row * 64 + t] = 0.0f;
    } else {
        size_t i = ((size_t)(b - 1024) * 256 + threadIdx.x) * 8;
        float4 f0 = *(const float4*)(queue + i);
        float4 f1 = *(const float4*)(queue + i + 4);
        short8 o;
        o[0] = bf_rne(f0.x); o[1] = bf_rne(f0.y); o[2] = bf_rne(f0.z); o[3] = bf_rne(f0.w);
        o[4] = bf_rne(f1.x); o[5] = bf_rne(f1.y); o[6] = bf_rne(f1.z); o[7] = bf_rne(f1.w);
        *(short8*)(qb + i) = o;
    }
}

// ---------- screen compute step: 16-q tile, k-outer / rf-inner (8-way ILP) ---
__device__ __forceinline__ void screen_tile(const short8 A[8][4],
                                            short8 b0, short8 b1, short8 b2, short8 b3,
                                            float rmax[8][4]) {
    floatx4 acc[8];
    floatx4 zero = {0.0f, 0.0f, 0.0f, 0.0f};
    #pragma unroll
    for (int rf = 0; rf < 8; ++rf) acc[rf] = MFMA16(A[rf][0], b0, zero);
    #pragma unroll
    for (int rf = 0; rf < 8; ++rf) acc[rf] = MFMA16(A[rf][1], b1, acc[rf]);
    #pragma unroll
    for (int rf = 0; rf < 8; ++rf) acc[rf] = MFMA16(A[rf][2], b2, acc[rf]);
    #pragma unroll
    for (int rf = 0; rf < 8; ++rf) acc[rf] = MFMA16(A[rf][3], b3, acc[rf]);
    #pragma unroll
    for (int rf = 0; rf < 8; ++rf)
        #pragma unroll
        for (int r = 0; r < 4; ++r) rmax[rf][r] = fmaxf(rmax[rf][r], acc[rf][r]);
}

// ---------- K2: single bf16 MFMA screen pass (round-2/6 proven, 86.5us) ------
// 794 TF ~= 87% of the plain-HIP 2-barrier-loop ceiling (m97-class ~900 TF);
// four structural variants (occupancy, 32x32, reg-pinning, deferred-fmax) all
// regressed -> this is the structure's ceiling; screen work stops here.
__global__ __launch_bounds__(256, 2) void k_screen(const short* __restrict__ pnb,
                                                   const short* __restrict__ qb,
                                                   unsigned int* __restrict__ mbest,
                                                   float* __restrict__ smax) {
    int tid = threadIdx.x;
    int lane = tid & 63, wv = tid >> 6;
    int n16 = lane & 15, quad = lane >> 4;

    int id = blockIdx.x;                // 0..511
    int xcd = id & 7;
    int g = id >> 3;                    // 0..63
    int rowblk = g & 7;                 // 8 rowblocks of 512 rows
    int qsub = g >> 3;                  // 0..7
    int qsplit = xcd * 8 + qsub;        // 64 qsplits of 1024 q, XCD-local
    int rowbase = rowblk * 512 + wv * 128;
    int qstart = qsplit * 1024;

    // A fragments: 8 row-groups x 4 k-groups, direct bf16 short8 loads.
    short8 A[8][4];
    #pragma unroll
    for (int rf = 0; rf < 8; ++rf) {
        const short* ap = pnb + (size_t)(rowbase + rf * 16 + n16) * 128 + quad * 8;
        #pragma unroll
        for (int kk = 0; kk < 4; ++kk)
            A[rf][kk] = *(const short8*)(ap + kk * 32);
    }
    #pragma unroll
    for (int rf = 0; rf < 8; ++rf)
        #pragma unroll
        for (int kk = 0; kk < 4; ++kk)
            asm volatile("" : "+v"(A[rf][kk]));   // keep A resident (neutral insurance)

    float rmax[8][4];
    #pragma unroll
    for (int rf = 0; rf < 8; ++rf)
        #pragma unroll
        for (int r = 0; r < 4; ++r) rmax[rf][r] = -1e30f;

    const short* lp = qb + (size_t)(qstart + n16) * 128 + quad * 8;
    // B buffer set 0 <- tile 0
    short8 a0 = *(const short8*)(lp), a1 = *(const short8*)(lp + 32),
           a2 = *(const short8*)(lp + 64), a3 = *(const short8*)(lp + 96);

    for (int t = 0; t < 64; t += 2) {
        if ((t & 15) == 0) __syncthreads();    // keep waves converged for B sharing
        // B buffer set 1 <- tile t+1
        const short* p1p = lp + 2048;
        short8 b0 = *(const short8*)(p1p), b1 = *(const short8*)(p1p + 32),
               b2 = *(const short8*)(p1p + 64), b3 = *(const short8*)(p1p + 96);
        // compute tile t (set 0)
        screen_tile(A, a0, a1, a2, a3, rmax);
        // B buffer set 0 <- tile t+2 (tail over-read lands in pnb region, unused)
        const short* p2p = lp + 4096;
        a0 = *(const short8*)(p2p); a1 = *(const short8*)(p2p + 32);
        a2 = *(const short8*)(p2p + 64); a3 = *(const short8*)(p2p + 96);
        // compute tile t+1 (set 1)
        screen_tile(A, b0, b1, b2, b3, rmax);
        lp += 4096;
    }

    #pragma unroll
    for (int rf = 0; rf < 8; ++rf)
        #pragma unroll
        for (int r = 0; r < 4; ++r) {
            float v = rmax[rf][r];
            v = fmaxf(v, __shfl_xor(v, 1));
            v = fmaxf(v, __shfl_xor(v, 2));
            v = fmaxf(v, __shfl_xor(v, 4));
            v = fmaxf(v, __shfl_xor(v, 8));
            if (n16 == 0) {
                int row = rowbase + rf * 16 + quad * 4 + r;
                atomicMax(&mbest[row], ordered_bits(v));
                smax[(size_t)qsplit * 4096 + row] = v;   // exact fp32 strip max
            }
        }
}

// ---------- K3: fused rescreen (row-scan + bf16 re-score + exact rerank) -----
// Grid 1024 = 64 strips x 16 qparts. Identical to round 6 (verified).
__global__ __launch_bounds__(256, 4) void k_rescreen(const short* __restrict__ pnb,
                                                     const short* __restrict__ qb,
                                                     const unsigned int* __restrict__ mbest,
                                                     const float* __restrict__ smax,
                                                     const float* __restrict__ pn,
                                                     const float* __restrict__ queue,
                                                     unsigned long long* __restrict__ best) {
    __shared__ unsigned short rows[SROWS_CAP];
    __shared__ int nsh;
    int b = blockIdx.x;
    int s = b & 63;                     // strip 0..63
    int qp = b >> 6;                    // 0..15
    int tid = threadIdx.x;
    if (tid == 0) nsh = 0;
    __syncthreads();
    const float* sm = smax + (size_t)s * 4096;
    #pragma unroll
    for (int j = 0; j < 16; ++j) {
        int row = tid + 256 * j;
        float thr = from_ordered(mbest[row]) - EPS_MARGIN;
        if (sm[row] > thr) {
            int pos = atomicAdd(&nsh, 1);
            if (pos < SROWS_CAP) rows[pos] = (unsigned short)row;
        }
    }
    __syncthreads();
    int n = nsh; if (n > SROWS_CAP) n = SROWS_CAP;
    if (n == 0) return;

    int lane = tid & 63, wv = tid >> 6;
    int n16 = lane & 15, quad = lane >> 4;
    int qt = qp * 4 + wv;               // q-tile 0..63 within strip
    int qrow = s * 1024 + qt * 16 + n16;    // this lane's q column index

    // B fragment (identical mapping to k_screen)
    const short* bp = qb + (size_t)qrow * 128 + quad * 8;
    short8 b0 = *(const short8*)(bp);
    short8 b1 = *(const short8*)(bp + 32);
    short8 b2 = *(const short8*)(bp + 64);
    short8 b3 = *(const short8*)(bp + 96);

    for (int base = 0; base < n; base += ROWCHUNK) {
        short8 Af[3][4]; float th[3][4]; int rowC[3][4];
        #pragma unroll
        for (int rt = 0; rt < 3; ++rt) {
            int ia = base + rt * 16 + n16;
            int rA = rows[ia < n ? ia : base];
            const short* ap = pnb + (size_t)rA * 128 + quad * 8;
            #pragma unroll
            for (int kk = 0; kk < 4; ++kk) Af[rt][kk] = *(const short8*)(ap + kk * 32);
            #pragma unroll
            for (int r = 0; r < 4; ++r) {
                int ic = base + rt * 16 + quad * 4 + r;
                if (ic < n) {
                    int rr = rows[ic];
                    rowC[rt][r] = rr;
                    th[rt][r] = from_ordered(mbest[rr]) - EPS_MARGIN;
                } else { rowC[rt][r] = 0; th[rt][r] = 3.0e38f; }
            }
        }
        #pragma unroll
        for (int rt = 0; rt < 3; ++rt) {
            floatx4 zero = {0.0f, 0.0f, 0.0f, 0.0f};
            floatx4 acc = MFMA16(Af[rt][0], b0, zero);
            acc = MFMA16(Af[rt][1], b1, acc);
            acc = MFMA16(Af[rt][2], b2, acc);
            acc = MFMA16(Af[rt][3], b3, acc);
            #pragma unroll
            for (int r = 0; r < 4; ++r) {
                unsigned long long mb = __ballot(acc[r] > th[rt][r]);
                while (mb) {            // rare path: exact fp32 rerank, whole wave
                    int L = __builtin_ctzll(mb);
                    mb &= mb - 1;
                    int row = __shfl(rowC[rt][r], L);
                    int q   = __shfl(qrow, L);
                    float2 a  = ((const float2*)(pn + (size_t)row * 128))[lane];
                    float2 bq = ((const float2*)(queue + (size_t)q * 128))[lane];
                    float d = a.x * bq.x + a.y * bq.y;
                    #pragma unroll
                    for (int o = 32; o; o >>= 1) d += __shfl_xor(d, o);
                    if (lane == 0) {
                        unsigned long long pk = ((unsigned long long)ordered_bits(d) << 32)
                                              | (unsigned long long)(unsigned int)(~q);
                        atomicMax(&best[row], pk);
                    }
                }
            }
        }
    }
}

// ---------- K4: MFMA gemm + lse partials (bf16 A x (bh+bl) B split) ----------
// Grid (16,16,2): block = 128 rows x 128 cols of matrix z. 4 waves x 32 rows.
// A: gathered queue rows -> bf16 frags DIRECTLY in registers (bit-identical
// quantization to the old nnb path; no LDS tile). B = pnb (hi) + pnl (lo
// residual): A*bh + A*bl keeps B at ~fp32 precision, so output error stays
// dominated by the unchanged A quantization. Replaces the fp32 LDS-tile GEMM
// whose ~2.1 GB LDS traffic put a ~31 us floor on it (69 TB/s LDS ceiling);
// MFMA work here is 4.3 GFLOP (~5 us class). Epilogue (exp/rowsum/colsum/
// diag) semantics identical.
__global__ __launch_bounds__(256, 2) void k_gemm_lse(const unsigned long long* __restrict__ best,
                                                     const float* __restrict__ queue,
                                                     const short* __restrict__ pnb,
                                                     const short* __restrict__ pnl,
                                                     float* __restrict__ sums,
                                                     float* __restrict__ dg) {
    __shared__ float red[4][128];
    int tid = threadIdx.x;
    int lane = tid & 63, wv = tid >> 6;
    int n16 = lane & 15, quad = lane >> 4;
    int z = blockIdx.z, xb = blockIdx.x, yb = blockIdx.y;

    // A: 2 row-frags (32 rows/wave) gathered from queue via best[].
    short8 A[2][4];
    #pragma unroll
    for (int rf = 0; rf < 2; ++rf) {
        int row = z * 2048 + xb * 128 + wv * 32 + rf * 16 + n16;
        unsigned int idx = (~(unsigned int)(best[row] & 0xFFFFFFFFull)) & 0xFFFFu;
        const float* qr = queue + (size_t)idx * 128 + quad * 8;
        #pragma unroll
        for (int kk = 0; kk < 4; ++kk) {
            float4 f0 = *(const float4*)(qr + kk * 32);
            float4 f1 = *(const float4*)(qr + kk * 32 + 4);
            short8 a;
            a[0] = bf_rne(f0.x); a[1] = bf_rne(f0.y); a[2] = bf_rne(f0.z); a[3] = bf_rne(f0.w);
            a[4] = bf_rne(f1.x); a[5] = bf_rne(f1.y); a[6] = bf_rne(f1.z); a[7] = bf_rne(f1.w);
            A[rf][kk] = a;
        }
    }

    int bbase = (z ? 0 : 2048) + yb * 128;      // B rows: p2n for z=0, p1n for z=1
    const short* bh0 = pnb + (size_t)(bbase + n16) * 128 + quad * 8;
    const short* bl0 = pnl + (size_t)(bbase + n16) * 128 + quad * 8;

    float rs[2][4] = {};
    float* rowsum = sums + z * 4096;
    float* colsum = sums + z * 4096 + 2048;

    #pragma unroll 1
    for (int ct = 0; ct < 8; ++ct) {            // 8 col-tiles of 16
        const short* ph = bh0 + (size_t)ct * 16 * 128;
        const short* pl = bl0 + (size_t)ct * 16 * 128;
        short8 h0 = *(const short8*)(ph),      h1 = *(const short8*)(ph + 32),
               h2 = *(const short8*)(ph + 64), h3 = *(const short8*)(ph + 96);
        short8 l0 = *(const short8*)(pl),      l1 = *(const short8*)(pl + 32),
               l2 = *(const short8*)(pl + 64), l3 = *(const short8*)(pl + 96);
        floatx4 acc0, acc1;
        floatx4 zero = {0.0f, 0.0f, 0.0f, 0.0f};
        acc0 = MFMA16(A[0][0], h0, zero); acc1 = MFMA16(A[1][0], h0, zero);
        acc0 = MFMA16(A[0][1], h1, acc0); acc1 = MFMA16(A[1][1], h1, acc1);
        acc0 = MFMA16(A[0][2], h2, acc0); acc1 = MFMA16(A[1][2], h2, acc1);
        acc0 = MFMA16(A[0][3], h3, acc0); acc1 = MFMA16(A[1][3], h3, acc1);
        acc0 = MFMA16(A[0][0], l0, acc0); acc1 = MFMA16(A[1][0], l0, acc1);
        acc0 = MFMA16(A[0][1], l1, acc0); acc1 = MFMA16(A[1][1], l1, acc1);
        acc0 = MFMA16(A[0][2], l2, acc0); acc1 = MFMA16(A[1][2], l2, acc1);
        acc0 = MFMA16(A[0][3], l3, acc0); acc1 = MFMA16(A[1][3], l3, acc1);

        float csv = 0.0f;
        #pragma unroll
        for (int rf = 0; rf < 2; ++rf)
            #pragma unroll
            for (int r = 0; r < 4; ++r) {
                float a = rf ? acc1[r] : acc0[r];
                int row_l = wv * 32 + rf * 16 + quad * 4 + r;
                if (xb == yb && row_l == ct * 16 + n16)
                    dg[z * 2048 + xb * 128 + row_l] = a;    // raw diag (pre-exp)
                float e = __expf(a * SCALE - 10.0f);
                rs[rf][r] += e;
                csv += e;
            }
        // col partial (this wave's 32 rows): reduce over quad lanes
        csv += __shfl_xor(csv, 16);
        csv += __shfl_xor(csv, 32);
        if (quad == 0) red[wv][ct * 16 + n16] = csv;
    }

    // row sums: reduce over the 16 n16 lanes, one atomicAdd per row
    #pragma unroll
    for (int rf = 0; rf < 2; ++rf)
        #pragma unroll
        for (int r = 0; r < 4; ++r) {
            float v = rs[rf][r];
            v += __shfl_xor(v, 1);
            v += __shfl_xor(v, 2);
            v += __shfl_xor(v, 4);
            v += __shfl_xor(v, 8);
            if (n16 == 0)
                atomicAdd(&rowsum[xb * 128 + wv * 32 + rf * 16 + quad * 4 + r], v);
        }

    __syncthreads();
    if (tid < 128) {
        float s = red[0][tid] + red[1][tid] + red[2][tid] + red[3][tid];
        atomicAdd(&colsum[yb * 128 + tid], s);
    }
}

// ---------- K5: final loss ----------
__global__ void k_final(const float* __restrict__ sums,
                        const float* __restrict__ dg1, const float* __restrict__ dg2,
                        float* __restrict__ out) {
    int idx = blockIdx.x * 256 + threadIdx.x;    // 0..8191
    int seg = idx >> 11, r = idx & 2047;
    float s = sums[seg * 2048 + r];
    float d = (seg < 2) ? dg1[r] : dg2[r];
    out[idx] = 10.0f + logf(s) - d * SCALE;
}

extern "C" void kernel_launch(void* const* d_in, const int* in_sizes, int n_in,
                              void* d_out, int out_size, void* d_ws, size_t ws_size,
                              hipStream_t stream) {
    const float* p1    = (const float*)d_in[0];   // [2048,128]
    const float* p2    = (const float*)d_in[1];   // [2048,128]
    const float* queue = (const float*)d_in[2];   // [65536,128]
    float* out = (float*)d_out;                   // [8192]

    char* w = (char*)d_ws;                        // footprint ~21.1 MiB
    float* pn   = (float*)w;                              // 2 MB fp32 [4096,128]
    float* smax = (float*)(w + (2u << 20));               // 1 MB fp32 [64,4096]
    short* qb   = (short*)(w + (3u << 20));               // 16 MB bf16 [65536,128]
    short* pnb  = (short*)(w + (19u << 20));              // 1 MB bf16 [4096,128] (hi)
    short* pnl  = (short*)(w + (20u << 20));              // 1 MB bf16 [4096,128] (lo)
    char* b2 = w + (21u << 20);
    unsigned int* mbest = (unsigned int*)b2;                        // 16 KB
    unsigned long long* best = (unsigned long long*)(b2 + (16u << 10)); // 32 KB
    float* sums = (float*)(b2 + (48u << 10));                       // 32 KB
    float* dg1  = sums + 8192;                                      // 8 KB
    float* dg2  = dg1 + 2048;                                       // 8 KB

    k_prep_qcvt<<<5120, 256, 0, stream>>>(p1, p2, queue, pn, pnb, pnl, qb, mbest, best, sums);
    k_screen<<<512, 256, 0, stream>>>(pnb, qb, mbest, smax);
    k_rescreen<<<64 * 16, 256, 0, stream>>>(pnb, qb, mbest, smax, pn, queue, best);
    k_gemm_lse<<<dim3(16, 16, 2), 256, 0, stream>>>(best, queue, pnb, pnl, sums, dg1);
    k_final<<<32, 256, 0, stream>>>(sums, dg1, dg2, out);
}

// Round 9
// 208.400 us; speedup vs baseline: 1.3819x; 1.0339x over previous
//
#include <hip/hip_runtime.h>

#define SCALE 10.0f           // 1 / TEMPERATURE
#define EPS_MARGIN 0.008f     // 2 * (bf16 unit-dot hard error bound)
#define SROWS_CAP 480         // per-strip flagged-row cap (expect ~85, sd ~9)
#define ROWCHUNK 48           // rows per rescreen chunk (3 x 16-row MFMA tiles)

typedef __attribute__((ext_vector_type(8))) short short8;
typedef __attribute__((ext_vector_type(4))) float floatx4;

#define MFMA16(a, b, c) __builtin_amdgcn_mfma_f32_16x16x32_bf16((a), (b), (c), 0, 0, 0)
#define SGB __builtin_amdgcn_sched_group_barrier

// ---------- helpers ----------
__device__ __forceinline__ unsigned int ordered_bits(float f) {
    unsigned int b = __float_as_uint(f);
    return (b & 0x80000000u) ? ~b : (b | 0x80000000u);
}
__device__ __forceinline__ float from_ordered(unsigned int u) {
    return __uint_as_float((u & 0x80000000u) ? (u ^ 0x80000000u) : ~u);
}
__device__ __forceinline__ short bf_rne(float x) {   // fp32 -> bf16 bits, RNE
    unsigned int u = __float_as_uint(x);
    return (short)((u + 0x7FFFu + ((u >> 16) & 1u)) >> 16);
}
__device__ __forceinline__ float bf2f(short s) {
    return __uint_as_float(((unsigned int)(unsigned short)s) << 16);
}

// ---------- K1: fused prep (l2-norm + hi/lo bf16 + init) and queue convert ---
__global__ __launch_bounds__(256) void k_prep_qcvt(const float* __restrict__ p1,
                                                   const float* __restrict__ p2,
                                                   const float* __restrict__ queue,
                                                   float* __restrict__ pn,
                                                   short* __restrict__ pnb,
                                                   short* __restrict__ pnl,
                                                   short* __restrict__ qb,
                                                   unsigned int* __restrict__ mbest,
                                                   unsigned long long* __restrict__ best,
                                                   float* __restrict__ sums) {
    int b = blockIdx.x;
    if (b < 1024) {
        int sub = threadIdx.x >> 6;     // wave 0..3 -> one row each
        int t = threadIdx.x & 63;
        int row = b * 4 + sub;          // 0..4095
        const float* src = (row < 2048) ? (p1 + (size_t)row * 128)
                                        : (p2 + (size_t)(row - 2048) * 128);
        float2 v = ((const float2*)src)[t];
        float ss = v.x * v.x + v.y * v.y;
        #pragma unroll
        for (int o = 32; o; o >>= 1) ss += __shfl_xor(ss, o);
        float inv = 1.0f / sqrtf(ss);
        float2 o2; o2.x = v.x * inv; o2.y = v.y * inv;
        ((float2*)(pn + (size_t)row * 128))[t] = o2;
        short hx = bf_rne(o2.x), hy = bf_rne(o2.y);
        unsigned int pk = (unsigned int)(unsigned short)hx
                        | ((unsigned int)(unsigned short)hy << 16);
        ((unsigned int*)(pnb + (size_t)row * 128))[t] = pk;
        short lx = bf_rne(o2.x - bf2f(hx)), ly = bf_rne(o2.y - bf2f(hy));
        unsigned int pl = (unsigned int)(unsigned short)lx
                        | ((unsigned int)(unsigned short)ly << 16);
        ((unsigned int*)(pnl + (size_t)row * 128))[t] = pl;
        if (t == 0) { mbest[row] = 0u; best[row] = 0ULL; }
        if (row < 128) sums[row * 64 + t] = 0.0f;
    } else {
        size_t i = ((size_t)(b - 1024) * 256 + threadIdx.x) * 8;
        float4 f0 = *(const float4*)(queue + i);
        float4 f1 = *(const float4*)(queue + i + 4);
        short8 o;
        o[0] = bf_rne(f0.x); o[1] = bf_rne(f0.y); o[2] = bf_rne(f0.z); o[3] = bf_rne(f0.w);
        o[4] = bf_rne(f1.x); o[5] = bf_rne(f1.y); o[6] = bf_rne(f1.z); o[7] = bf_rne(f1.w);
        *(short8*)(qb + i) = o;
    }
}

// ---------- screen primitives ----------
__device__ __forceinline__ void loadB4(short8 B[4], const short* p) {
    B[0] = *(const short8*)(p);
    B[1] = *(const short8*)(p + 32);
    B[2] = *(const short8*)(p + 64);
    B[3] = *(const short8*)(p + 96);
}
// Half-tile chain: 4 row-frags x K=128 against one 16-q B tile (16 MFMA).
__device__ __forceinline__ void chainH(const short8 (*Ah)[4], const short8 B[4],
                                       floatx4 acc[4]) {
    floatx4 zero = {0.0f, 0.0f, 0.0f, 0.0f};
    #pragma unroll
    for (int i = 0; i < 4; ++i) acc[i] = MFMA16(Ah[i][0], B[0], zero);
    #pragma unroll
    for (int i = 0; i < 4; ++i) acc[i] = MFMA16(Ah[i][1], B[1], acc[i]);
    #pragma unroll
    for (int i = 0; i < 4; ++i) acc[i] = MFMA16(Ah[i][2], B[2], acc[i]);
    #pragma unroll
    for (int i = 0; i < 4; ++i) acc[i] = MFMA16(Ah[i][3], B[3], acc[i]);
}
__device__ __forceinline__ void fmaxH(float (*rm)[4], const floatx4 acc[4]) {
    #pragma unroll
    for (int i = 0; i < 4; ++i)
        #pragma unroll
        for (int r = 0; r < 4; ++r) rm[i][r] = fmaxf(rm[i][r], acc[i][r]);
}

// ---------- K2: bf16 MFMA screen, half-tile-deferred fmax ---------------------
// Geometry IDENTICAL to the proven round-2/6/8 structure (512 blocks = 8
// rowblocks x 64 strips, 4 waves, rf=8 A[8][4] resident, B reg-dbuf, (256,2)).
// ONLY change: acc[8] split into two half-tile buffers accP/accQ, with each
// half's fmax deferred until AFTER the next half-chain issues -- the old
// same-tile MFMA->fmax dependency drained the matrix pipe every tile (3244
// cyc/tile vs 620 cyc of MFMA work = 80% idle at MfmaUtil 31%). Now >=16
// MFMAs are always queued between a chain's last issue and its consumer.
// sched_group_barrier script pins the {VMEM,MFMA,VALU} interleave so the
// experiment is decisive. fmax reordering across tiles is max-commutative ->
// rmax bit-exact -> certificate semantics unchanged. Zero register growth.
__global__ __launch_bounds__(256, 2) void k_screen(const short* __restrict__ pnb,
                                                   const short* __restrict__ qb,
                                                   unsigned int* __restrict__ mbest,
                                                   float* __restrict__ smax) {
    int tid = threadIdx.x;
    int lane = tid & 63, wv = tid >> 6;
    int n16 = lane & 15, quad = lane >> 4;

    int id = blockIdx.x;                // 0..511
    int xcd = id & 7;
    int g = id >> 3;                    // 0..63
    int rowblk = g & 7;                 // 8 rowblocks of 512 rows
    int qsub = g >> 3;                  // 0..7
    int qsplit = xcd * 8 + qsub;        // 64 qsplits of 1024 q, XCD-local
    int rowbase = rowblk * 512 + wv * 128;
    int qstart = qsplit * 1024;

    // A fragments: 8 row-groups x 4 k-groups, direct bf16 short8 loads.
    short8 A[8][4];
    #pragma unroll
    for (int rf = 0; rf < 8; ++rf) {
        const short* ap = pnb + (size_t)(rowbase + rf * 16 + n16) * 128 + quad * 8;
        #pragma unroll
        for (int kk = 0; kk < 4; ++kk)
            A[rf][kk] = *(const short8*)(ap + kk * 32);
    }
    #pragma unroll
    for (int rf = 0; rf < 8; ++rf)
        #pragma unroll
        for (int kk = 0; kk < 4; ++kk)
            asm volatile("" : "+v"(A[rf][kk]));   // keep A resident (neutral insurance)

    float rmax[8][4];
    #pragma unroll
    for (int rf = 0; rf < 8; ++rf)
        #pragma unroll
        for (int r = 0; r < 4; ++r) rmax[rf][r] = -1e30f;

    const short* lp = qb + (size_t)(qstart + n16) * 128 + quad * 8;
    short8 Ba[4], Bb[4];
    floatx4 accP[4], accQ[4];

    // prologue: tile 0 (Ba), tile 1 prefetched (Bb)
    loadB4(Ba, lp);
    loadB4(Bb, lp + 2048);
    chainH(A,     Ba, accP);            // t0 H0
    chainH(A + 4, Ba, accQ);            // t0 H1
    fmaxH(rmax,     accP);              // t0 H0 (one-time immediate)
    // pending: accQ = t0 H1

    for (int t = 1; t < 63; t += 2) {
        if (((t - 1) & 15) == 0) __syncthreads();   // keep waves converged
        loadB4(Ba, lp + (size_t)(t + 1) * 2048);    // tile t+1
        chainH(A,     Bb, accP);        // t   H0
        fmaxH(rmax + 4, accQ);          // t-1 H1 (>=16 MFMA since its chain)
        chainH(A + 4, Bb, accQ);        // t   H1
        fmaxH(rmax,     accP);          // t   H0
        loadB4(Bb, lp + (size_t)(t + 2) * 2048);    // tile t+2
        chainH(A,     Ba, accP);        // t+1 H0
        fmaxH(rmax + 4, accQ);          // t   H1
        chainH(A + 4, Ba, accQ);        // t+1 H1
        fmaxH(rmax,     accP);          // t+1 H0
        // pin the interleave (per-iteration emission order):
        SGB(0x20, 4, 0);                // 4 VMEM_READ (tile t+1)
        SGB(0x8, 16, 0); SGB(0x2, 16, 0);
        SGB(0x8, 16, 0); SGB(0x2, 16, 0);
        SGB(0x20, 4, 0);                // 4 VMEM_READ (tile t+2)
        SGB(0x8, 16, 0); SGB(0x2, 16, 0);
        SGB(0x8, 16, 0); SGB(0x2, 16, 0);
    }
    // epilogue: tile 63 in Bb; pending accQ = t62 H1
    chainH(A,     Bb, accP);            // t63 H0
    fmaxH(rmax + 4, accQ);              // t62 H1
    chainH(A + 4, Bb, accQ);            // t63 H1
    fmaxH(rmax,     accP);              // t63 H0
    fmaxH(rmax + 4, accQ);              // t63 H1

    #pragma unroll
    for (int rf = 0; rf < 8; ++rf)
        #pragma unroll
        for (int r = 0; r < 4; ++r) {
            float v = rmax[rf][r];
            v = fmaxf(v, __shfl_xor(v, 1));
            v = fmaxf(v, __shfl_xor(v, 2));
            v = fmaxf(v, __shfl_xor(v, 4));
            v = fmaxf(v, __shfl_xor(v, 8));
            if (n16 == 0) {
                int row = rowbase + rf * 16 + quad * 4 + r;
                atomicMax(&mbest[row], ordered_bits(v));
                smax[(size_t)qsplit * 4096 + row] = v;   // exact fp32 strip max
            }
        }
}

// ---------- K3: fused rescreen (row-scan + bf16 re-score + exact rerank) -----
// Grid 1024 = 64 strips x 16 qparts. Identical to rounds 6/8 (verified).
__global__ __launch_bounds__(256, 4) void k_rescreen(const short* __restrict__ pnb,
                                                     const short* __restrict__ qb,
                                                     const unsigned int* __restrict__ mbest,
                                                     const float* __restrict__ smax,
                                                     const float* __restrict__ pn,
                                                     const float* __restrict__ queue,
                                                     unsigned long long* __restrict__ best) {
    __shared__ unsigned short rows[SROWS_CAP];
    __shared__ int nsh;
    int b = blockIdx.x;
    int s = b & 63;                     // strip 0..63
    int qp = b >> 6;                    // 0..15
    int tid = threadIdx.x;
    if (tid == 0) nsh = 0;
    __syncthreads();
    const float* sm = smax + (size_t)s * 4096;
    #pragma unroll
    for (int j = 0; j < 16; ++j) {
        int row = tid + 256 * j;
        float thr = from_ordered(mbest[row]) - EPS_MARGIN;
        if (sm[row] > thr) {
            int pos = atomicAdd(&nsh, 1);
            if (pos < SROWS_CAP) rows[pos] = (unsigned short)row;
        }
    }
    __syncthreads();
    int n = nsh; if (n > SROWS_CAP) n = SROWS_CAP;
    if (n == 0) return;

    int lane = tid & 63, wv = tid >> 6;
    int n16 = lane & 15, quad = lane >> 4;
    int qt = qp * 4 + wv;               // q-tile 0..63 within strip
    int qrow = s * 1024 + qt * 16 + n16;    // this lane's q column index

    // B fragment (identical mapping to k_screen)
    const short* bp = qb + (size_t)qrow * 128 + quad * 8;
    short8 b0 = *(const short8*)(bp);
    short8 b1 = *(const short8*)(bp + 32);
    short8 b2 = *(const short8*)(bp + 64);
    short8 b3 = *(const short8*)(bp + 96);

    for (int base = 0; base < n; base += ROWCHUNK) {
        short8 Af[3][4]; float th[3][4]; int rowC[3][4];
        #pragma unroll
        for (int rt = 0; rt < 3; ++rt) {
            int ia = base + rt * 16 + n16;
            int rA = rows[ia < n ? ia : base];
            const short* ap = pnb + (size_t)rA * 128 + quad * 8;
            #pragma unroll
            for (int kk = 0; kk < 4; ++kk) Af[rt][kk] = *(const short8*)(ap + kk * 32);
            #pragma unroll
            for (int r = 0; r < 4; ++r) {
                int ic = base + rt * 16 + quad * 4 + r;
                if (ic < n) {
                    int rr = rows[ic];
                    rowC[rt][r] = rr;
                    th[rt][r] = from_ordered(mbest[rr]) - EPS_MARGIN;
                } else { rowC[rt][r] = 0; th[rt][r] = 3.0e38f; }
            }
        }
        #pragma unroll
        for (int rt = 0; rt < 3; ++rt) {
            floatx4 zero = {0.0f, 0.0f, 0.0f, 0.0f};
            floatx4 acc = MFMA16(Af[rt][0], b0, zero);
            acc = MFMA16(Af[rt][1], b1, acc);
            acc = MFMA16(Af[rt][2], b2, acc);
            acc = MFMA16(Af[rt][3], b3, acc);
            #pragma unroll
            for (int r = 0; r < 4; ++r) {
                unsigned long long mb = __ballot(acc[r] > th[rt][r]);
                while (mb) {            // rare path: exact fp32 rerank, whole wave
                    int L = __builtin_ctzll(mb);
                    mb &= mb - 1;
                    int row = __shfl(rowC[rt][r], L);
                    int q   = __shfl(qrow, L);
                    float2 a  = ((const float2*)(pn + (size_t)row * 128))[lane];
                    float2 bq = ((const float2*)(queue + (size_t)q * 128))[lane];
                    float d = a.x * bq.x + a.y * bq.y;
                    #pragma unroll
                    for (int o = 32; o; o >>= 1) d += __shfl_xor(d, o);
                    if (lane == 0) {
                        unsigned long long pk = ((unsigned long long)ordered_bits(d) << 32)
                                              | (unsigned long long)(unsigned int)(~q);
                        atomicMax(&best[row], pk);
                    }
                }
            }
        }
    }
}

// ---------- K4: MFMA gemm + lse partials (bf16 A x (bh+bl) B split) ----------
// Identical to round 8 (verified; saved ~19 us vs the fp32 LDS-tile GEMM).
__global__ __launch_bounds__(256, 2) void k_gemm_lse(const unsigned long long* __restrict__ best,
                                                     const float* __restrict__ queue,
                                                     const short* __restrict__ pnb,
                                                     const short* __restrict__ pnl,
                                                     float* __restrict__ sums,
                                                     float* __restrict__ dg) {
    __shared__ float red[4][128];
    int tid = threadIdx.x;
    int lane = tid & 63, wv = tid >> 6;
    int n16 = lane & 15, quad = lane >> 4;
    int z = blockIdx.z, xb = blockIdx.x, yb = blockIdx.y;

    // A: 2 row-frags (32 rows/wave) gathered from queue via best[].
    short8 A[2][4];
    #pragma unroll
    for (int rf = 0; rf < 2; ++rf) {
        int row = z * 2048 + xb * 128 + wv * 32 + rf * 16 + n16;
        unsigned int idx = (~(unsigned int)(best[row] & 0xFFFFFFFFull)) & 0xFFFFu;
        const float* qr = queue + (size_t)idx * 128 + quad * 8;
        #pragma unroll
        for (int kk = 0; kk < 4; ++kk) {
            float4 f0 = *(const float4*)(qr + kk * 32);
            float4 f1 = *(const float4*)(qr + kk * 32 + 4);
            short8 a;
            a[0] = bf_rne(f0.x); a[1] = bf_rne(f0.y); a[2] = bf_rne(f0.z); a[3] = bf_rne(f0.w);
            a[4] = bf_rne(f1.x); a[5] = bf_rne(f1.y); a[6] = bf_rne(f1.z); a[7] = bf_rne(f1.w);
            A[rf][kk] = a;
        }
    }

    int bbase = (z ? 0 : 2048) + yb * 128;      // B rows: p2n for z=0, p1n for z=1
    const short* bh0 = pnb + (size_t)(bbase + n16) * 128 + quad * 8;
    const short* bl0 = pnl + (size_t)(bbase + n16) * 128 + quad * 8;

    float rs[2][4] = {};
    float* rowsum = sums + z * 4096;
    float* colsum = sums + z * 4096 + 2048;

    #pragma unroll 1
    for (int ct = 0; ct < 8; ++ct) {            // 8 col-tiles of 16
        const short* ph = bh0 + (size_t)ct * 16 * 128;
        const short* pl = bl0 + (size_t)ct * 16 * 128;
        short8 h0 = *(const short8*)(ph),      h1 = *(const short8*)(ph + 32),
               h2 = *(const short8*)(ph + 64), h3 = *(const short8*)(ph + 96);
        short8 l0 = *(const short8*)(pl),      l1 = *(const short8*)(pl + 32),
               l2 = *(const short8*)(pl + 64), l3 = *(const short8*)(pl + 96);
        floatx4 acc0, acc1;
        floatx4 zero = {0.0f, 0.0f, 0.0f, 0.0f};
        acc0 = MFMA16(A[0][0], h0, zero); acc1 = MFMA16(A[1][0], h0, zero);
        acc0 = MFMA16(A[0][1], h1, acc0); acc1 = MFMA16(A[1][1], h1, acc1);
        acc0 = MFMA16(A[0][2], h2, acc0); acc1 = MFMA16(A[1][2], h2, acc1);
        acc0 = MFMA16(A[0][3], h3, acc0); acc1 = MFMA16(A[1][3], h3, acc1);
        acc0 = MFMA16(A[0][0], l0, acc0); acc1 = MFMA16(A[1][0], l0, acc1);
        acc0 = MFMA16(A[0][1], l1, acc0); acc1 = MFMA16(A[1][1], l1, acc1);
        acc0 = MFMA16(A[0][2], l2, acc0); acc1 = MFMA16(A[1][2], l2, acc1);
        acc0 = MFMA16(A[0][3], l3, acc0); acc1 = MFMA16(A[1][3], l3, acc1);

        float csv = 0.0f;
        #pragma unroll
        for (int rf = 0; rf < 2; ++rf)
            #pragma unroll
            for (int r = 0; r < 4; ++r) {
                float a = rf ? acc1[r] : acc0[r];
                int row_l = wv * 32 + rf * 16 + quad * 4 + r;
                if (xb == yb && row_l == ct * 16 + n16)
                    dg[z * 2048 + xb * 128 + row_l] = a;    // raw diag (pre-exp)
                float e = __expf(a * SCALE - 10.0f);
                rs[rf][r] += e;
                csv += e;
            }
        // col partial (this wave's 32 rows): reduce over quad lanes
        csv += __shfl_xor(csv, 16);
        csv += __shfl_xor(csv, 32);
        if (quad == 0) red[wv][ct * 16 + n16] = csv;
    }

    // row sums: reduce over the 16 n16 lanes, one atomicAdd per row
    #pragma unroll
    for (int rf = 0; rf < 2; ++rf)
        #pragma unroll
        for (int r = 0; r < 4; ++r) {
            float v = rs[rf][r];
            v += __shfl_xor(v, 1);
            v += __shfl_xor(v, 2);
            v += __shfl_xor(v, 4);
            v += __shfl_xor(v, 8);
            if (n16 == 0)
                atomicAdd(&rowsum[xb * 128 + wv * 32 + rf * 16 + quad * 4 + r], v);
        }

    __syncthreads();
    if (tid < 128) {
        float s = red[0][tid] + red[1][tid] + red[2][tid] + red[3][tid];
        atomicAdd(&colsum[yb * 128 + tid], s);
    }
}

// ---------- K5: final loss ----------
__global__ void k_final(const float* __restrict__ sums,
                        const float* __restrict__ dg1, const float* __restrict__ dg2,
                        float* __restrict__ out) {
    int idx = blockIdx.x * 256 + threadIdx.x;    // 0..8191
    int seg = idx >> 11, r = idx & 2047;
    float s = sums[seg * 2048 + r];
    float d = (seg < 2) ? dg1[r] : dg2[r];
    out[idx] = 10.0f + logf(s) - d * SCALE;
}

extern "C" void kernel_launch(void* const* d_in, const int* in_sizes, int n_in,
                              void* d_out, int out_size, void* d_ws, size_t ws_size,
                              hipStream_t stream) {
    const float* p1    = (const float*)d_in[0];   // [2048,128]
    const float* p2    = (const float*)d_in[1];   // [2048,128]
    const float* queue = (const float*)d_in[2];   // [65536,128]
    float* out = (float*)d_out;                   // [8192]

    char* w = (char*)d_ws;                        // footprint ~21.1 MiB
    float* pn   = (float*)w;                              // 2 MB fp32 [4096,128]
    float* smax = (float*)(w + (2u << 20));               // 1 MB fp32 [64,4096]
    short* qb   = (short*)(w + (3u << 20));               // 16 MB bf16 [65536,128]
    short* pnb  = (short*)(w + (19u << 20));              // 1 MB bf16 [4096,128] (hi)
    short* pnl  = (short*)(w + (20u << 20));              // 1 MB bf16 [4096,128] (lo)
    char* b2 = w + (21u << 20);
    unsigned int* mbest = (unsigned int*)b2;                        // 16 KB
    unsigned long long* best = (unsigned long long*)(b2 + (16u << 10)); // 32 KB
    float* sums = (float*)(b2 + (48u << 10));                       // 32 KB
    float* dg1  = sums + 8192;                                      // 8 KB
    float* dg2  = dg1 + 2048;                                       // 8 KB

    k_prep_qcvt<<<5120, 256, 0, stream>>>(p1, p2, queue, pn, pnb, pnl, qb, mbest, best, sums);
    k_screen<<<512, 256, 0, stream>>>(pnb, qb, mbest, smax);
    k_rescreen<<<64 * 16, 256, 0, stream>>>(pnb, qb, mbest, smax, pn, queue, best);
    k_gemm_lse<<<dim3(16, 16, 2), 256, 0, stream>>>(best, queue, pnb, pnl, sums, dg1);
    k_final<<<32, 256, 0, stream>>>(sums, dg1, dg2, out);
}